// Round 5
// baseline (1992.382 us; speedup 1.0000x reference)
//
#include <hip/hip_runtime.h>

// GraphAE: 2x GCNConv encoder + 2-layer MLP decoder.
// N=50000, IN=128, HID=256, LAT=64, E=800000. fp32 in/out.
//
// R15 changes vs R14:
//  - ALL 11 kernels fused into one persistent-block kernel (grid=1024,
//    __launch_bounds__(256,4): VGPR<=128 + 32KB LDS -> 4 blocks/CU guaranteed
//    co-resident on 256 CUs). Hand-rolled sense-reversing grid barrier with
//    agent-scope __hip_atomic_* + __threadfence (cross-XCD L2 wb/inv), bounded
//    spin (wrong-results-not-hang on failure). R14 showed all our kernels
//    < 42us with 13 serialized dispatches -> suspected ~100us of dispatch
//    gaps. wsplit now overlaps scan1 (blocks >= nblk). Phase math identical
//    to R14 (absmax must stay 2.441e-4).
//  - R14: f16 gather planes (xs/zs), confirmed -32us.
//  - R11: hist/fill dst-range partitioned 8 ways (part = pb&7, preserved).
// (R10: GEMM fusions via 32KB LDS frag tiles; R8: MFMA-frag-tiled hi/lo bf16.)

#define IN_CH  128
#define HIDDEN 256
#define LATENT 64
#define GRIDB  1024

typedef unsigned short u16;
typedef unsigned int u32;
typedef __bf16 bf16x8 __attribute__((ext_vector_type(8)));
typedef float f32x4 __attribute__((ext_vector_type(4)));
typedef _Float16 f16x4 __attribute__((ext_vector_type(4)));

static __device__ __forceinline__ float4 ld4(const float* p) {
    return *reinterpret_cast<const float4*>(p);
}
static __device__ __forceinline__ void acc4(float4& a, float4 v) {
    a.x += v.x; a.y += v.y; a.z += v.z; a.w += v.w;
}
static __device__ __forceinline__ f16x4 ldh4(const _Float16* p) {
    return *reinterpret_cast<const f16x4*>(p);
}
static __device__ __forceinline__ void acch(float4& a, f16x4 v) {
    a.x += (float)v[0]; a.y += (float)v[1]; a.z += (float)v[2]; a.w += (float)v[3];
}

// truncating hi/lo split: hi = top16(v); lo = top16(v - hi). v-hi exact.
static __device__ __forceinline__ void split_bf16(float v, u16& hi, u16& lo) {
    u32 b = __float_as_uint(v);
    hi = (u16)(b >> 16);
    float hf = __uint_as_float(b & 0xFFFF0000u);
    lo = (u16)(__float_as_uint(v - hf) >> 16);
}

// tiled-layout offset (elements). K multiple of 8; row tiles of 16.
static __device__ __forceinline__ long tix(int row, int k, int K) {
    return ((long)(row >> 4) * (K >> 3) + (k >> 3)) * 128 + ((row & 15) << 3) + (k & 7);
}

#define MFMA3(ACC, AH, AL, BH, BL)                                             \
    ACC = __builtin_amdgcn_mfma_f32_16x16x32_bf16(AH, BH, ACC, 0, 0, 0);       \
    ACC = __builtin_amdgcn_mfma_f32_16x16x32_bf16(AH, BL, ACC, 0, 0, 0);       \
    ACC = __builtin_amdgcn_mfma_f32_16x16x32_bf16(AL, BH, ACC, 0, 0, 0);

// Grid barrier: sense-reversing, device(agent)-scope. bar[0]=count, bar[1]=gen.
// __threadfence() before arrival flushes this XCD's dirty L2 lines (release);
// after release, acquires + __threadfence() invalidate stale lines.
// Bounded spin: on failure results go wrong (verify catches), never a hang.
static __device__ __forceinline__ void gsync(int* bar) {
    __syncthreads();
    if (threadIdx.x == 0) {
        __threadfence();
        int my_gen = __hip_atomic_load(&bar[1], __ATOMIC_RELAXED, __HIP_MEMORY_SCOPE_AGENT);
        int arrived = __hip_atomic_fetch_add(&bar[0], 1, __ATOMIC_ACQ_REL, __HIP_MEMORY_SCOPE_AGENT);
        if (arrived == GRIDB - 1) {
            __hip_atomic_store(&bar[0], 0, __ATOMIC_RELAXED, __HIP_MEMORY_SCOPE_AGENT);
            __hip_atomic_fetch_add(&bar[1], 1, __ATOMIC_RELEASE, __HIP_MEMORY_SCOPE_AGENT);
        } else {
            long guard = 0;
            while (__hip_atomic_load(&bar[1], __ATOMIC_ACQUIRE, __HIP_MEMORY_SCOPE_AGENT) == my_gen &&
                   guard < (1L << 31)) guard++;
        }
        __threadfence();
    }
    __syncthreads();
}

__global__ __launch_bounds__(256, 4) void fused_all(
    const float* __restrict__ x, const int* __restrict__ ei,
    const float* __restrict__ W1, const float* __restrict__ b1,
    const float* __restrict__ W2, const float* __restrict__ b2,
    const float* __restrict__ Wd1, const float* __restrict__ bd1,
    const float* __restrict__ Wd2, const float* __restrict__ bd2,
    float* __restrict__ out,
    int* __restrict__ counts, int* __restrict__ rowptr, int* __restrict__ nxt,
    int* __restrict__ blocksums, int* __restrict__ blockoffs,
    float* __restrict__ dinv, int* __restrict__ col,
    _Float16* __restrict__ xsh, u16* __restrict__ xa_hi, u16* __restrict__ xa_lo,
    _Float16* __restrict__ zsh, u16* __restrict__ z_hi, u16* __restrict__ z_lo,
    u16* __restrict__ w1h, u16* __restrict__ w1l, u16* __restrict__ w2h, u16* __restrict__ w2l,
    u16* __restrict__ wd1h, u16* __restrict__ wd1l, u16* __restrict__ wd2h, u16* __restrict__ wd2l,
    int* __restrict__ bar, int N, int E) {
    __shared__ u16 lds[2][32 * 256];  // 32 KB; aliased as int[] for scans

    const int tid = threadIdx.x;
    const int pb = blockIdx.x;
    const int wid = tid >> 6, lane = tid & 63, quad = lane >> 4, lm = lane & 15;
    const int nper = (N + 7) / 8;
    const int chunks = (E + 255) / 256;
    const int nblk = (N + 255) / 256;
    const int total4 = N * (IN_CH / 4);
    const int fblk = (N + 31) / 32;
    const int nb4 = (N + 3) / 4;

    // ---- phase 0: zero counts[0..N] ----
    for (int i = pb * 256 + tid; i <= N; i += GRIDB * 256) counts[i] = 0;
    gsync(bar);

    // ---- phase 1: hist (dst-partitioned, part = pb&7 ~ XCD) ----
    {
        const int part = pb & 7;
        for (int ch = pb >> 3; ch < chunks; ch += GRIDB >> 3) {
            int e = ch * 256 + tid;
            if (e < E) {
                int d = ei[E + e];
                if ((unsigned)(d - part * nper) < (unsigned)nper) atomicAdd(&counts[d], 1);
            }
        }
    }
    gsync(bar);

    // ---- phase 2: scan1 (pb < nblk) || wsplit (pb >= nblk, concurrent) ----
    if (pb < nblk) {
        int* sh = (int*)&lds[0][0];
        int i = pb * 256 + tid;
        int v = (i < N) ? counts[i] : 0;
        if (i < N) dinv[i] = rsqrtf((float)v + 1.0f);
        sh[tid] = v;
        __syncthreads();
        for (int off = 1; off < 256; off <<= 1) {
            int t = (tid >= off) ? sh[tid - off] : 0;
            __syncthreads();
            sh[tid] += t;
            __syncthreads();
        }
        if (i < N) rowptr[i] = sh[tid] - v;
        if (tid == 255) blocksums[pb] = sh[255];
    } else {
        for (int idx = (pb - nblk) * 256 + tid; idx < 98304; idx += (GRIDB - nblk) * 256) {
            const float* W; u16 *H, *L; int K, Nn, base;
            if (idx < 32768)      { W = W1;  H = w1h;  L = w1l;  K = 128; Nn = 256; base = idx; }
            else if (idx < 49152) { W = W2;  H = w2h;  L = w2l;  K = 256; Nn = 64;  base = idx - 32768; }
            else if (idx < 65536) { W = Wd1; H = wd1h; L = wd1l; K = 64;  Nn = 256; base = idx - 49152; }
            else                  { W = Wd2; H = wd2h; L = wd2l; K = 256; Nn = 128; base = idx - 65536; }
            int k = base / Nn, n = base % Nn;
            u16 h, l;
            split_bf16(W[base], h, l);
            long o = tix(n, k, K);
            H[o] = h;
            L[o] = l;
        }
    }
    gsync(bar);

    // ---- phase 3: scan2 (pb == 0) ----
    if (pb == 0) {
        int* sh = (int*)&lds[0][0];
        int v = (tid < nblk) ? blocksums[tid] : 0;
        sh[tid] = v;
        __syncthreads();
        for (int off = 1; off < 256; off <<= 1) {
            int t = (tid >= off) ? sh[tid - off] : 0;
            __syncthreads();
            sh[tid] += t;
            __syncthreads();
        }
        if (tid < nblk) blockoffs[tid] = sh[tid] - v;
        if (tid == nblk - 1) rowptr[N] = sh[tid];
    }
    gsync(bar);

    // ---- phase 4: scan3 (finalize rowptr, init nxt) + prescale xs=dinv*x (f16) ----
    for (int i = pb * 256 + tid; i < total4; i += GRIDB * 256) {
        if (i < N) {
            int r = rowptr[i] + blockoffs[i >> 8];
            rowptr[i] = r;
            nxt[i] = r;
        }
        float s = dinv[i >> 5];
        float4 v = ld4(&x[(long)i * 4]);
        f16x4 h;
        h[0] = (_Float16)(v.x * s);
        h[1] = (_Float16)(v.y * s);
        h[2] = (_Float16)(v.z * s);
        h[3] = (_Float16)(v.w * s);
        *reinterpret_cast<f16x4*>(&xsh[(long)i * 4]) = h;
    }
    gsync(bar);

    // ---- phase 5: fill (dst-partitioned CSR fill) ----
    {
        const int part = pb & 7;
        for (int ch = pb >> 3; ch < chunks; ch += GRIDB >> 3) {
            int e = ch * 256 + tid;
            if (e < E) {
                int d = ei[E + e];
                if ((unsigned)(d - part * nper) < (unsigned)nper) {
                    int s = ei[e];
                    int pos = atomicAdd(&nxt[d], 1);
                    col[pos] = s;
                }
            }
        }
    }
    gsync(bar);

    // ---- phase 6: aggx — xa[i] = dinv[i]*(xs[i]+sum_in xs[s]); f16 gather ----
    for (int vb = pb; vb < nb4; vb += GRIDB) {
        int node = vb * 4 + wid;
        if (node < N) {
            int slot = lane >> 5;
            int c = (lane & 31) * 4;
            float4 a0 = make_float4(0.f, 0.f, 0.f, 0.f);
            float4 a1 = a0, a2 = a0, a3 = a0;
            if (slot == 0) acch(a0, ldh4(&xsh[(long)node * 128 + c]));
            int beg = rowptr[node];
            int end = rowptr[node + 1];
            for (int cb = beg; cb < end; cb += 64) {
                int cnt = min(64, end - cb);
                int cv = (lane < cnt) ? col[cb + lane] : 0;
                int full = cnt >> 1;
                int trips = (cnt + 1) >> 1;
                int t = 0;
                for (; t + 4 <= full; t += 4) {
                    int j = slot + 2 * t;
                    int s0 = __shfl(cv, j);
                    int s1 = __shfl(cv, j + 2);
                    int s2 = __shfl(cv, j + 4);
                    int s3 = __shfl(cv, j + 6);
                    f16x4 v0 = ldh4(&xsh[(long)s0 * 128 + c]);
                    f16x4 v1 = ldh4(&xsh[(long)s1 * 128 + c]);
                    f16x4 v2 = ldh4(&xsh[(long)s2 * 128 + c]);
                    f16x4 v3 = ldh4(&xsh[(long)s3 * 128 + c]);
                    acch(a0, v0); acch(a1, v1); acch(a2, v2); acch(a3, v3);
                }
                for (; t < trips; t++) {
                    int j = slot + 2 * t;
                    bool p = j < cnt;
                    int s = __shfl(cv, p ? j : 0);
                    if (p) acch(a0, ldh4(&xsh[(long)s * 128 + c]));
                }
            }
            acc4(a0, a1); acc4(a2, a3); acc4(a0, a2);
            a0.x += __shfl_xor(a0.x, 32);
            a0.y += __shfl_xor(a0.y, 32);
            a0.z += __shfl_xor(a0.z, 32);
            a0.w += __shfl_xor(a0.w, 32);
            if (slot == 0) {
                float di = dinv[node];
                a0.x *= di; a0.y *= di; a0.z *= di; a0.w *= di;
                ushort4 h, l;
                split_bf16(a0.x, h.x, l.x);
                split_bf16(a0.y, h.y, l.y);
                split_bf16(a0.z, h.z, l.z);
                split_bf16(a0.w, h.w, l.w);
                long o = tix(node, c, 128);
                *(ushort4*)&xa_hi[o] = h;
                *(ushort4*)&xa_lo[o] = l;
            }
        }
    }
    gsync(bar);

    // ---- phase 7: enc — zs = (relu(xa@W1+b1) @ W2) * dinv (f16 out) ----
    for (int vb = pb; vb < fblk; vb += GRIDB) {
        const int rt0 = vb * 2;
        const int last_rt = (N >> 4) - 1;

        f32x4 acc[2][4];
#pragma unroll
        for (int i = 0; i < 2; i++)
#pragma unroll
            for (int j = 0; j < 4; j++) acc[i][j] = (f32x4){0.f, 0.f, 0.f, 0.f};

#pragma unroll
        for (int kc = 0; kc < 4; kc++) {
            const int kb = kc * 4 + quad;
            bf16x8 ah[2], al[2], bh[4], bl[4];
#pragma unroll
            for (int i = 0; i < 2; i++) {
                int rt = rt0 + i; rt = rt <= last_rt ? rt : last_rt;
                long o = ((long)rt * 16 + kb) * 128 + lm * 8;
                ah[i] = *(const bf16x8*)&xa_hi[o];
                al[i] = *(const bf16x8*)&xa_lo[o];
            }
#pragma unroll
            for (int j = 0; j < 4; j++) {
                long o = ((long)(wid * 4 + j) * 16 + kb) * 128 + lm * 8;
                bh[j] = *(const bf16x8*)&w1h[o];
                bl[j] = *(const bf16x8*)&w1l[o];
            }
#pragma unroll
            for (int i = 0; i < 2; i++)
#pragma unroll
                for (int j = 0; j < 4; j++) { MFMA3(acc[i][j], ah[i], al[i], bh[j], bl[j]); }
        }

#pragma unroll
        for (int i = 0; i < 2; i++)
#pragma unroll
            for (int j = 0; j < 4; j++) {
                int coln = wid * 64 + j * 16 + lm;
                float bi = b1[coln];
#pragma unroll
                for (int r = 0; r < 4; r++) {
                    int row = i * 16 + quad * 4 + r;
                    float v = fmaxf(acc[i][j][r] + bi, 0.f);
                    u16 h, l;
                    split_bf16(v, h, l);
                    int o = ((row >> 4) * 32 + (coln >> 3)) * 128 + ((row & 15) << 3) + (coln & 7);
                    lds[0][o] = h;
                    lds[1][o] = l;
                }
            }
        __syncthreads();

        f32x4 acc2[2];
        acc2[0] = (f32x4){0.f, 0.f, 0.f, 0.f};
        acc2[1] = (f32x4){0.f, 0.f, 0.f, 0.f};
#pragma unroll
        for (int kc = 0; kc < 8; kc++) {
            const int kb = kc * 4 + quad;
            bf16x8 ah[2], al[2], bh, bl;
#pragma unroll
            for (int i = 0; i < 2; i++) {
                int o = (i * 32 + kb) * 128 + lm * 8;
                ah[i] = *(const bf16x8*)&lds[0][o];
                al[i] = *(const bf16x8*)&lds[1][o];
            }
            {
                long o = ((long)wid * 32 + kb) * 128 + lm * 8;
                bh = *(const bf16x8*)&w2h[o];
                bl = *(const bf16x8*)&w2l[o];
            }
#pragma unroll
            for (int i = 0; i < 2; i++) { MFMA3(acc2[i], ah[i], al[i], bh, bl); }
        }
#pragma unroll
        for (int i = 0; i < 2; i++) {
            int coln = wid * 16 + lm;
#pragma unroll
            for (int r = 0; r < 4; r++) {
                int row = rt0 * 16 + i * 16 + quad * 4 + r;
                if (row < N) zsh[(long)row * 64 + coln] = (_Float16)(acc2[i][r] * dinv[row]);
            }
        }
        __syncthreads();  // protect LDS reuse across vb iterations
    }
    gsync(bar);

    // ---- phase 8: agg64 — z = dinv*(zs+sum zs)+b2; f16 gather ----
    for (int vb = pb; vb < nb4; vb += GRIDB) {
        int node = vb * 4 + wid;
        if (node < N) {
            int slot = lane >> 4;
            int c = (lane & 15) * 4;
            float4 a0 = make_float4(0.f, 0.f, 0.f, 0.f);
            float4 a1 = a0, a2 = a0, a3 = a0;
            if (slot == 0) acch(a0, ldh4(&zsh[(long)node * 64 + c]));
            int beg = rowptr[node];
            int end = rowptr[node + 1];
            for (int cb = beg; cb < end; cb += 64) {
                int cnt = min(64, end - cb);
                int cv = (lane < cnt) ? col[cb + lane] : 0;
                int full = cnt >> 2;
                int trips = (cnt + 3) >> 2;
                int t = 0;
                for (; t + 4 <= full; t += 4) {
                    int j = slot + 4 * t;
                    int s0 = __shfl(cv, j);
                    int s1 = __shfl(cv, j + 4);
                    int s2 = __shfl(cv, j + 8);
                    int s3 = __shfl(cv, j + 12);
                    f16x4 v0 = ldh4(&zsh[(long)s0 * 64 + c]);
                    f16x4 v1 = ldh4(&zsh[(long)s1 * 64 + c]);
                    f16x4 v2 = ldh4(&zsh[(long)s2 * 64 + c]);
                    f16x4 v3 = ldh4(&zsh[(long)s3 * 64 + c]);
                    acch(a0, v0); acch(a1, v1); acch(a2, v2); acch(a3, v3);
                }
                for (; t < trips; t++) {
                    int j = slot + 4 * t;
                    bool p = j < cnt;
                    int s = __shfl(cv, p ? j : 0);
                    if (p) acch(a0, ldh4(&zsh[(long)s * 64 + c]));
                }
            }
            acc4(a0, a1); acc4(a2, a3); acc4(a0, a2);
            a0.x += __shfl_xor(a0.x, 16); a0.x += __shfl_xor(a0.x, 32);
            a0.y += __shfl_xor(a0.y, 16); a0.y += __shfl_xor(a0.y, 32);
            a0.z += __shfl_xor(a0.z, 16); a0.z += __shfl_xor(a0.z, 32);
            a0.w += __shfl_xor(a0.w, 16); a0.w += __shfl_xor(a0.w, 32);
            if (slot == 0) {
                float di = dinv[node];
                float4 bi = ld4(&b2[c]);
                a0.x = a0.x * di + bi.x;
                a0.y = a0.y * di + bi.y;
                a0.z = a0.z * di + bi.z;
                a0.w = a0.w * di + bi.w;
                ushort4 h, l;
                split_bf16(a0.x, h.x, l.x);
                split_bf16(a0.y, h.y, l.y);
                split_bf16(a0.z, h.z, l.z);
                split_bf16(a0.w, h.w, l.w);
                long o = tix(node, c, 64);
                *(ushort4*)&z_hi[o] = h;
                *(ushort4*)&z_lo[o] = l;
            }
        }
    }
    gsync(bar);

    // ---- phase 9: dec — out = relu(z@Wd1+bd1)@Wd2 + bd2 ----
    for (int vb = pb; vb < fblk; vb += GRIDB) {
        const int rt0 = vb * 2;
        const int last_rt = (N >> 4) - 1;

        f32x4 acc[2][4];
#pragma unroll
        for (int i = 0; i < 2; i++)
#pragma unroll
            for (int j = 0; j < 4; j++) acc[i][j] = (f32x4){0.f, 0.f, 0.f, 0.f};

#pragma unroll
        for (int kc = 0; kc < 2; kc++) {
            const int kb = kc * 4 + quad;
            bf16x8 ah[2], al[2], bh[4], bl[4];
#pragma unroll
            for (int i = 0; i < 2; i++) {
                int rt = rt0 + i; rt = rt <= last_rt ? rt : last_rt;
                long o = ((long)rt * 8 + kb) * 128 + lm * 8;
                ah[i] = *(const bf16x8*)&z_hi[o];
                al[i] = *(const bf16x8*)&z_lo[o];
            }
#pragma unroll
            for (int j = 0; j < 4; j++) {
                long o = ((long)(wid * 4 + j) * 8 + kb) * 128 + lm * 8;
                bh[j] = *(const bf16x8*)&wd1h[o];
                bl[j] = *(const bf16x8*)&wd1l[o];
            }
#pragma unroll
            for (int i = 0; i < 2; i++)
#pragma unroll
                for (int j = 0; j < 4; j++) { MFMA3(acc[i][j], ah[i], al[i], bh[j], bl[j]); }
        }

#pragma unroll
        for (int i = 0; i < 2; i++)
#pragma unroll
            for (int j = 0; j < 4; j++) {
                int coln = wid * 64 + j * 16 + lm;
                float bi = bd1[coln];
#pragma unroll
                for (int r = 0; r < 4; r++) {
                    int row = i * 16 + quad * 4 + r;
                    float v = fmaxf(acc[i][j][r] + bi, 0.f);
                    u16 h, l;
                    split_bf16(v, h, l);
                    int o = ((row >> 4) * 32 + (coln >> 3)) * 128 + ((row & 15) << 3) + (coln & 7);
                    lds[0][o] = h;
                    lds[1][o] = l;
                }
            }
        __syncthreads();

        f32x4 acc2[2][2];
#pragma unroll
        for (int i = 0; i < 2; i++)
#pragma unroll
            for (int j = 0; j < 2; j++) acc2[i][j] = (f32x4){0.f, 0.f, 0.f, 0.f};
#pragma unroll
        for (int kc = 0; kc < 8; kc++) {
            const int kb = kc * 4 + quad;
            bf16x8 ah[2], al[2], bh[2], bl[2];
#pragma unroll
            for (int i = 0; i < 2; i++) {
                int o = (i * 32 + kb) * 128 + lm * 8;
                ah[i] = *(const bf16x8*)&lds[0][o];
                al[i] = *(const bf16x8*)&lds[1][o];
            }
#pragma unroll
            for (int j = 0; j < 2; j++) {
                long o = ((long)(wid * 2 + j) * 32 + kb) * 128 + lm * 8;
                bh[j] = *(const bf16x8*)&wd2h[o];
                bl[j] = *(const bf16x8*)&wd2l[o];
            }
#pragma unroll
            for (int i = 0; i < 2; i++)
#pragma unroll
                for (int j = 0; j < 2; j++) { MFMA3(acc2[i][j], ah[i], al[i], bh[j], bl[j]); }
        }
#pragma unroll
        for (int i = 0; i < 2; i++)
#pragma unroll
            for (int j = 0; j < 2; j++) {
                int coln = wid * 32 + j * 16 + lm;
                float bi = bd2[coln];
#pragma unroll
                for (int r = 0; r < 4; r++) {
                    int row = rt0 * 16 + i * 16 + quad * 4 + r;
                    if (row < N) out[(long)row * 128 + coln] = acc2[i][j][r] + bi;
                }
            }
        __syncthreads();  // protect LDS reuse across vb iterations
    }
}

// ---------------- launch ----------------

extern "C" void kernel_launch(void* const* d_in, const int* in_sizes, int n_in,
                              void* d_out, int out_size, void* d_ws, size_t ws_size,
                              hipStream_t stream) {
    const float* x        = (const float*)d_in[0];
    const int* ei         = (const int*)d_in[1];   // int32 (harness integer convention)
    const float* W1       = (const float*)d_in[2];
    const float* b1       = (const float*)d_in[3];
    const float* W2       = (const float*)d_in[4];
    const float* b2       = (const float*)d_in[5];
    const float* Wd1      = (const float*)d_in[6];
    const float* bd1      = (const float*)d_in[7];
    const float* Wd2      = (const float*)d_in[8];
    const float* bd2      = (const float*)d_in[9];
    float* out            = (float*)d_out;

    const int N = in_sizes[0] / IN_CH;   // 50000 (multiple of 16)
    const int E = in_sizes[1] / 2;       // 800000

    char* p = (char*)d_ws;
    auto alloc = [&](size_t bytes) {
        char* r = p;
        p += (bytes + 255) & ~(size_t)255;
        return r;
    };
    int*      counts    = (int*)     alloc((size_t)(N + 1) * 4);
    int*      rowptr    = (int*)     alloc((size_t)(N + 1) * 4);
    int*      nxt       = (int*)     alloc((size_t)N * 4);
    int*      blocksums = (int*)     alloc(256 * 4);
    int*      blockoffs = (int*)     alloc(256 * 4);
    float*    dinv      = (float*)   alloc((size_t)N * 4);
    int*      col       = (int*)     alloc((size_t)E * 4);
    _Float16* xsh       = (_Float16*)alloc((size_t)N * IN_CH * 2);
    u16*      xa_hi     = (u16*)     alloc((size_t)N * IN_CH * 2);
    u16*      xa_lo     = (u16*)     alloc((size_t)N * IN_CH * 2);
    _Float16* zsh       = (_Float16*)alloc((size_t)N * LATENT * 2);
    u16*      z_hi      = (u16*)     alloc((size_t)N * LATENT * 2);
    u16*      z_lo      = (u16*)     alloc((size_t)N * LATENT * 2);
    u16*      w1t_hi    = (u16*)     alloc((size_t)IN_CH * HIDDEN * 2);
    u16*      w1t_lo    = (u16*)     alloc((size_t)IN_CH * HIDDEN * 2);
    u16*      w2t_hi    = (u16*)     alloc((size_t)HIDDEN * LATENT * 2);
    u16*      w2t_lo    = (u16*)     alloc((size_t)HIDDEN * LATENT * 2);
    u16*      wd1t_hi   = (u16*)     alloc((size_t)LATENT * HIDDEN * 2);
    u16*      wd1t_lo   = (u16*)     alloc((size_t)LATENT * HIDDEN * 2);
    u16*      wd2t_hi   = (u16*)     alloc((size_t)HIDDEN * IN_CH * 2);
    u16*      wd2t_lo   = (u16*)     alloc((size_t)HIDDEN * IN_CH * 2);
    int*      bar       = (int*)     alloc(256);

    // barrier state must start at 0 every iteration (ws is re-poisoned)
    hipMemsetAsync(bar, 0, 16, stream);

    fused_all<<<GRIDB, 256, 0, stream>>>(
        x, ei, W1, b1, W2, b2, Wd1, bd1, Wd2, bd2, out,
        counts, rowptr, nxt, blocksums, blockoffs, dinv, col,
        xsh, xa_hi, xa_lo, zsh, z_hi, z_lo,
        w1t_hi, w1t_lo, w2t_hi, w2t_lo, wd1t_hi, wd1t_lo, wd2t_hi, wd2t_lo,
        bar, N, E);
}

// Round 6
// 326.377 us; speedup vs baseline: 6.1045x; 6.1045x over previous
//
#include <hip/hip_runtime.h>

// GraphAE: 2x GCNConv encoder + 2-layer MLP decoder.
// N=50000, IN=128, HID=256, LAT=64, E=800000. fp32 in/out.
//
// R16 changes vs R15/R14:
//  - R15 REVERTED (grid-barrier fusion: 1992us, chip 98% idle; agent-scope
//    acquire spin = per-poll L2 invalidate on non-coherent XCD L2s. Journal:
//    spin-barrier full fusion is dead on gfx950).
//  - Producer-consumer fusion WITHOUT barriers, at matching block granularity:
//    * aggx fused into enc as per-block prologue: each of 4 waves aggregates
//      8 nodes (f16 gather, fp32 acc) -> 16KB LDS bf16 hi/lo tile; stage A
//      reads frags from LDS. xa planes (51.2MB round trip) + 1 dispatch gone.
//    * agg64 fused into dec the same way (8KB LDS z tile): z planes (25.6MB)
//      + 1 dispatch gone. Gather blocks overlap MFMA blocks across CUs.
//    * wsplit rides in scan1's dispatch (blocks >= nblk).
//    * scan2 folded into scan3: block b needs only blockoffs[b] =
//      sum(blocksums[0..b)) - computed per block. 12 dispatches -> 7.
//  - R14: f16 gather planes (confirmed -32us). R11: hist/fill dst-partition.
// (R10: GEMM fusions via 32KB LDS frag tiles; R8: MFMA-frag-tiled hi/lo bf16.)

#define IN_CH  128
#define HIDDEN 256
#define LATENT 64

typedef unsigned short u16;
typedef unsigned int u32;
typedef __bf16 bf16x8 __attribute__((ext_vector_type(8)));
typedef float f32x4 __attribute__((ext_vector_type(4)));
typedef _Float16 f16x4 __attribute__((ext_vector_type(4)));

static __device__ __forceinline__ float4 ld4(const float* p) {
    return *reinterpret_cast<const float4*>(p);
}
static __device__ __forceinline__ void acc4(float4& a, float4 v) {
    a.x += v.x; a.y += v.y; a.z += v.z; a.w += v.w;
}
static __device__ __forceinline__ f16x4 ldh4(const _Float16* p) {
    return *reinterpret_cast<const f16x4*>(p);
}
static __device__ __forceinline__ void acch(float4& a, f16x4 v) {
    a.x += (float)v[0]; a.y += (float)v[1]; a.z += (float)v[2]; a.w += (float)v[3];
}

// truncating hi/lo split: hi = top16(v); lo = top16(v - hi). v-hi exact.
static __device__ __forceinline__ void split_bf16(float v, u16& hi, u16& lo) {
    u32 b = __float_as_uint(v);
    hi = (u16)(b >> 16);
    float hf = __uint_as_float(b & 0xFFFF0000u);
    lo = (u16)(__float_as_uint(v - hf) >> 16);
}

// tiled-layout offset (elements). K multiple of 8; row tiles of 16.
static __device__ __forceinline__ long tix(int row, int k, int K) {
    return ((long)(row >> 4) * (K >> 3) + (k >> 3)) * 128 + ((row & 15) << 3) + (k & 7);
}

#define MFMA3(ACC, AH, AL, BH, BL)                                             \
    ACC = __builtin_amdgcn_mfma_f32_16x16x32_bf16(AH, BH, ACC, 0, 0, 0);       \
    ACC = __builtin_amdgcn_mfma_f32_16x16x32_bf16(AH, BL, ACC, 0, 0, 0);       \
    ACC = __builtin_amdgcn_mfma_f32_16x16x32_bf16(AL, BH, ACC, 0, 0, 0);

// ---------------- graph structure kernels ----------------

// Partitioned histogram: block b handles edge chunk (b>>3), dst range (b&7).
__global__ void hist_kernel(const int* __restrict__ ei, int E,
                            int* __restrict__ counts, int nper) {
    int part = blockIdx.x & 7;
    int e = (blockIdx.x >> 3) * 256 + threadIdx.x;
    if (e >= E) return;
    int d = ei[E + e];
    if ((unsigned)(d - part * nper) < (unsigned)nper) atomicAdd(&counts[d], 1);
}

// scan1 (blocks < nblk) with dinv emit; wsplit rides along (blocks >= nblk).
__global__ void scan1_wsplit_kernel(
    const int* __restrict__ counts, int* __restrict__ rowptr,
    int* __restrict__ blocksums, float* __restrict__ dinv, int N, int nblk,
    const float* __restrict__ W1, const float* __restrict__ W2,
    const float* __restrict__ Wd1, const float* __restrict__ Wd2,
    u16* __restrict__ w1h, u16* __restrict__ w1l, u16* __restrict__ w2h, u16* __restrict__ w2l,
    u16* __restrict__ wd1h, u16* __restrict__ wd1l, u16* __restrict__ wd2h, u16* __restrict__ wd2l) {
    __shared__ int sh[256];
    int tid = threadIdx.x;
    if ((int)blockIdx.x < nblk) {
        int i = blockIdx.x * 256 + tid;
        int v = (i < N) ? counts[i] : 0;
        if (i < N) dinv[i] = rsqrtf((float)v + 1.0f);
        sh[tid] = v;
        __syncthreads();
        for (int off = 1; off < 256; off <<= 1) {
            int t = (tid >= off) ? sh[tid - off] : 0;
            __syncthreads();
            sh[tid] += t;
            __syncthreads();
        }
        if (i < N) rowptr[i] = sh[tid] - v;
        if (tid == 255) blocksums[blockIdx.x] = sh[255];
    } else {
        int idx = ((int)blockIdx.x - nblk) * 256 + tid;
        if (idx < 98304) {
            const float* W; u16 *H, *L; int K, Nn, base;
            if (idx < 32768)      { W = W1;  H = w1h;  L = w1l;  K = 128; Nn = 256; base = idx; }
            else if (idx < 49152) { W = W2;  H = w2h;  L = w2l;  K = 256; Nn = 64;  base = idx - 32768; }
            else if (idx < 65536) { W = Wd1; H = wd1h; L = wd1l; K = 64;  Nn = 256; base = idx - 49152; }
            else                  { W = Wd2; H = wd2h; L = wd2l; K = 256; Nn = 128; base = idx - 65536; }
            int k = base / Nn, n = base % Nn;
            u16 h, l;
            split_bf16(W[base], h, l);
            long o = tix(n, k, K);
            H[o] = h;
            L[o] = l;
        }
    }
}

// scan3 (+inlined scan2: blockoffs[b] = sum blocksums[0..b)) + prescale.
__global__ void scan3_prescale_kernel(
    int* __restrict__ rowptr, const int* __restrict__ blocksums, int* __restrict__ next,
    const float* __restrict__ x, const float* __restrict__ dinv, _Float16* __restrict__ xsh,
    int N, int total4, int nblk) {
    __shared__ int sh[256];
    const int b = blockIdx.x;
    const int tid = threadIdx.x;
    int boff = 0;
    if (b < nblk) {
        int s = 0;
        for (int j = tid; j < b; j += 256) s += blocksums[j];
        sh[tid] = s;
        __syncthreads();
        for (int off = 128; off > 0; off >>= 1) {
            if (tid < off) sh[tid] += sh[tid + off];
            __syncthreads();
        }
        boff = sh[0];
        if (b == nblk - 1 && tid == 0) rowptr[N] = boff + blocksums[b];
    }
    int i = b * 256 + tid;
    if (b < nblk && i < N) {
        int r = rowptr[i] + boff;
        rowptr[i] = r;
        next[i] = r;
    }
    if (i < total4) {
        float s = dinv[i >> 5];
        float4 v = ld4(&x[(long)i * 4]);
        f16x4 h;
        h[0] = (_Float16)(v.x * s);
        h[1] = (_Float16)(v.y * s);
        h[2] = (_Float16)(v.z * s);
        h[3] = (_Float16)(v.w * s);
        *reinterpret_cast<f16x4*>(&xsh[(long)i * 4]) = h;
    }
}

// Partitioned CSR fill: block b handles edge chunk (b>>3), dst range (b&7).
__global__ void fill_kernel(const int* __restrict__ ei, int E,
                            int* __restrict__ next, int* __restrict__ col, int nper) {
    int part = blockIdx.x & 7;
    int e = (blockIdx.x >> 3) * 256 + threadIdx.x;
    if (e >= E) return;
    int d = ei[E + e];
    if ((unsigned)(d - part * nper) < (unsigned)nper) {
        int s = ei[e];
        int pos = atomicAdd(&next[d], 1);
        col[pos] = s;
    }
}

// ---------------- fused agg+encoder ----------------
// Prologue: each wave aggregates 8 nodes (f16 gather, fp32 acc, dinv scale)
// -> 16KB LDS bf16 hi/lo xa tile [32 rows x 128]. Then:
// zs = (relu(xa@W1+b1) @ W2) * dinv, frag loads from LDS.
__global__ __launch_bounds__(256) void enc_fused(
    const _Float16* __restrict__ xsh, const int* __restrict__ rowptr,
    const int* __restrict__ col, const float* __restrict__ dinv,
    const u16* __restrict__ w1h, const u16* __restrict__ w1l,
    const u16* __restrict__ w2h, const u16* __restrict__ w2l,
    const float* __restrict__ b1, _Float16* __restrict__ zsh, int M) {
    __shared__ u16 o1[2][32 * 256];  // 32 KB (stage A -> stage B)
    __shared__ u16 xa[2][32 * 128];  // 16 KB (agg -> stage A)

    const int tid = threadIdx.x;
    const int wid = tid >> 6, lane = tid & 63, quad = lane >> 4, lm = lane & 15;
    const int rt0 = blockIdx.x * 2;
    const int last_rt = (M >> 4) - 1;

    // ---- agg prologue (aggx): 8 nodes per wave ----
    {
        const int slot = lane >> 5;
        const int c = (lane & 31) * 4;
        for (int r8 = 0; r8 < 8; r8++) {
            int node = blockIdx.x * 32 + wid * 8 + r8;
            if (node >= M) break;
            float4 a0 = make_float4(0.f, 0.f, 0.f, 0.f);
            float4 a1 = a0, a2 = a0, a3 = a0;
            if (slot == 0) acch(a0, ldh4(&xsh[(long)node * 128 + c]));
            int beg = rowptr[node];
            int end = rowptr[node + 1];
            for (int cb = beg; cb < end; cb += 64) {
                int cnt = min(64, end - cb);
                int cv = (lane < cnt) ? col[cb + lane] : 0;
                int full = cnt >> 1;
                int trips = (cnt + 1) >> 1;
                int t = 0;
                for (; t + 4 <= full; t += 4) {
                    int j = slot + 2 * t;
                    int s0 = __shfl(cv, j);
                    int s1 = __shfl(cv, j + 2);
                    int s2 = __shfl(cv, j + 4);
                    int s3 = __shfl(cv, j + 6);
                    f16x4 v0 = ldh4(&xsh[(long)s0 * 128 + c]);
                    f16x4 v1 = ldh4(&xsh[(long)s1 * 128 + c]);
                    f16x4 v2 = ldh4(&xsh[(long)s2 * 128 + c]);
                    f16x4 v3 = ldh4(&xsh[(long)s3 * 128 + c]);
                    acch(a0, v0); acch(a1, v1); acch(a2, v2); acch(a3, v3);
                }
                for (; t < trips; t++) {
                    int j = slot + 2 * t;
                    bool p = j < cnt;
                    int s = __shfl(cv, p ? j : 0);
                    if (p) acch(a0, ldh4(&xsh[(long)s * 128 + c]));
                }
            }
            acc4(a0, a1); acc4(a2, a3); acc4(a0, a2);
            a0.x += __shfl_xor(a0.x, 32);
            a0.y += __shfl_xor(a0.y, 32);
            a0.z += __shfl_xor(a0.z, 32);
            a0.w += __shfl_xor(a0.w, 32);
            if (slot == 0) {
                float di = dinv[node];
                a0.x *= di; a0.y *= di; a0.z *= di; a0.w *= di;
                ushort4 h, l;
                split_bf16(a0.x, h.x, l.x);
                split_bf16(a0.y, h.y, l.y);
                split_bf16(a0.z, h.z, l.z);
                split_bf16(a0.w, h.w, l.w);
                int row = wid * 8 + r8;
                int o = ((row >> 4) * 16 + (c >> 3)) * 128 + ((row & 15) << 3) + (c & 7);
                *(ushort4*)&xa[0][o] = h;
                *(ushort4*)&xa[1][o] = l;
            }
        }
    }
    __syncthreads();

    // ---- stage A: out1 = relu(xa @ W1 + b1), K=128 (KB=16, KC=4) ----
    f32x4 acc[2][4];
#pragma unroll
    for (int i = 0; i < 2; i++)
#pragma unroll
        for (int j = 0; j < 4; j++) acc[i][j] = (f32x4){0.f, 0.f, 0.f, 0.f};

#pragma unroll
    for (int kc = 0; kc < 4; kc++) {
        const int kb = kc * 4 + quad;
        bf16x8 ah[2], al[2], bh[4], bl[4];
#pragma unroll
        for (int i = 0; i < 2; i++) {
            int lt = (rt0 + i <= last_rt) ? i : (last_rt - rt0);
            int o = (lt * 16 + kb) * 128 + lm * 8;
            ah[i] = *(const bf16x8*)&xa[0][o];
            al[i] = *(const bf16x8*)&xa[1][o];
        }
#pragma unroll
        for (int j = 0; j < 4; j++) {
            long o = ((long)(wid * 4 + j) * 16 + kb) * 128 + lm * 8;
            bh[j] = *(const bf16x8*)&w1h[o];
            bl[j] = *(const bf16x8*)&w1l[o];
        }
#pragma unroll
        for (int i = 0; i < 2; i++)
#pragma unroll
            for (int j = 0; j < 4; j++) { MFMA3(acc[i][j], ah[i], al[i], bh[j], bl[j]); }
    }

    // epilogue A -> LDS tiled
#pragma unroll
    for (int i = 0; i < 2; i++)
#pragma unroll
        for (int j = 0; j < 4; j++) {
            int coln = wid * 64 + j * 16 + lm;
            float bi = b1[coln];
#pragma unroll
            for (int r = 0; r < 4; r++) {
                int row = i * 16 + quad * 4 + r;
                float v = fmaxf(acc[i][j][r] + bi, 0.f);
                u16 h, l;
                split_bf16(v, h, l);
                int o = ((row >> 4) * 32 + (coln >> 3)) * 128 + ((row & 15) << 3) + (coln & 7);
                o1[0][o] = h;
                o1[1][o] = l;
            }
        }
    __syncthreads();

    // ---- stage B: zs = (out1 @ W2) * dinv, K=256 (KB=32, KC=8) ----
    f32x4 acc2[2];
    acc2[0] = (f32x4){0.f, 0.f, 0.f, 0.f};
    acc2[1] = (f32x4){0.f, 0.f, 0.f, 0.f};
#pragma unroll
    for (int kc = 0; kc < 8; kc++) {
        const int kb = kc * 4 + quad;
        bf16x8 ah[2], al[2], bh, bl;
#pragma unroll
        for (int i = 0; i < 2; i++) {
            int o = (i * 32 + kb) * 128 + lm * 8;
            ah[i] = *(const bf16x8*)&o1[0][o];
            al[i] = *(const bf16x8*)&o1[1][o];
        }
        {
            long o = ((long)wid * 32 + kb) * 128 + lm * 8;
            bh = *(const bf16x8*)&w2h[o];
            bl = *(const bf16x8*)&w2l[o];
        }
#pragma unroll
        for (int i = 0; i < 2; i++) { MFMA3(acc2[i], ah[i], al[i], bh, bl); }
    }
#pragma unroll
    for (int i = 0; i < 2; i++) {
        int coln = wid * 16 + lm;
#pragma unroll
        for (int r = 0; r < 4; r++) {
            int row = rt0 * 16 + i * 16 + quad * 4 + r;
            if (row < M) zsh[(long)row * 64 + coln] = (_Float16)(acc2[i][r] * dinv[row]);
        }
    }
}

// ---------------- fused agg+decoder ----------------
// Prologue: each wave aggregates 8 nodes of z = dinv*(zs+sum zs)+b2 -> 8KB
// LDS bf16 hi/lo z tile [32 x 64]. Then out = relu(z@Wd1+bd1)@Wd2 + bd2.
__global__ __launch_bounds__(256) void dec_fused(
    const _Float16* __restrict__ zsh, const int* __restrict__ rowptr,
    const int* __restrict__ col, const float* __restrict__ dinv,
    const float* __restrict__ b2,
    const u16* __restrict__ wd1h, const u16* __restrict__ wd1l,
    const u16* __restrict__ wd2h, const u16* __restrict__ wd2l,
    const float* __restrict__ bd1, const float* __restrict__ bd2,
    float* __restrict__ out, int M) {
    __shared__ u16 dsm[2][32 * 256];  // 32 KB (stage A -> stage B)
    __shared__ u16 zt[2][32 * 64];    // 8 KB (agg -> stage A)

    const int tid = threadIdx.x;
    const int wid = tid >> 6, lane = tid & 63, quad = lane >> 4, lm = lane & 15;
    const int rt0 = blockIdx.x * 2;
    const int last_rt = (M >> 4) - 1;

    // ---- agg prologue (agg64): 8 nodes per wave ----
    {
        const int slot = lane >> 4;
        const int c = (lane & 15) * 4;
        for (int r8 = 0; r8 < 8; r8++) {
            int node = blockIdx.x * 32 + wid * 8 + r8;
            if (node >= M) break;
            float4 a0 = make_float4(0.f, 0.f, 0.f, 0.f);
            float4 a1 = a0, a2 = a0, a3 = a0;
            if (slot == 0) acch(a0, ldh4(&zsh[(long)node * 64 + c]));
            int beg = rowptr[node];
            int end = rowptr[node + 1];
            for (int cb = beg; cb < end; cb += 64) {
                int cnt = min(64, end - cb);
                int cv = (lane < cnt) ? col[cb + lane] : 0;
                int full = cnt >> 2;
                int trips = (cnt + 3) >> 2;
                int t = 0;
                for (; t + 4 <= full; t += 4) {
                    int j = slot + 4 * t;
                    int s0 = __shfl(cv, j);
                    int s1 = __shfl(cv, j + 4);
                    int s2 = __shfl(cv, j + 8);
                    int s3 = __shfl(cv, j + 12);
                    f16x4 v0 = ldh4(&zsh[(long)s0 * 64 + c]);
                    f16x4 v1 = ldh4(&zsh[(long)s1 * 64 + c]);
                    f16x4 v2 = ldh4(&zsh[(long)s2 * 64 + c]);
                    f16x4 v3 = ldh4(&zsh[(long)s3 * 64 + c]);
                    acch(a0, v0); acch(a1, v1); acch(a2, v2); acch(a3, v3);
                }
                for (; t < trips; t++) {
                    int j = slot + 4 * t;
                    bool p = j < cnt;
                    int s = __shfl(cv, p ? j : 0);
                    if (p) acch(a0, ldh4(&zsh[(long)s * 64 + c]));
                }
            }
            acc4(a0, a1); acc4(a2, a3); acc4(a0, a2);
            a0.x += __shfl_xor(a0.x, 16); a0.x += __shfl_xor(a0.x, 32);
            a0.y += __shfl_xor(a0.y, 16); a0.y += __shfl_xor(a0.y, 32);
            a0.z += __shfl_xor(a0.z, 16); a0.z += __shfl_xor(a0.z, 32);
            a0.w += __shfl_xor(a0.w, 16); a0.w += __shfl_xor(a0.w, 32);
            if (slot == 0) {
                float di = dinv[node];
                float4 bi = ld4(&b2[c]);
                a0.x = a0.x * di + bi.x;
                a0.y = a0.y * di + bi.y;
                a0.z = a0.z * di + bi.z;
                a0.w = a0.w * di + bi.w;
                ushort4 h, l;
                split_bf16(a0.x, h.x, l.x);
                split_bf16(a0.y, h.y, l.y);
                split_bf16(a0.z, h.z, l.z);
                split_bf16(a0.w, h.w, l.w);
                int row = wid * 8 + r8;
                int o = ((row >> 4) * 8 + (c >> 3)) * 128 + ((row & 15) << 3) + (c & 7);
                *(ushort4*)&zt[0][o] = h;
                *(ushort4*)&zt[1][o] = l;
            }
        }
    }
    __syncthreads();

    // ---- stage A: d = relu(z @ Wd1 + bd1), K=64 (KB=8, KC=2) ----
    f32x4 acc[2][4];
#pragma unroll
    for (int i = 0; i < 2; i++)
#pragma unroll
        for (int j = 0; j < 4; j++) acc[i][j] = (f32x4){0.f, 0.f, 0.f, 0.f};

#pragma unroll
    for (int kc = 0; kc < 2; kc++) {
        const int kb = kc * 4 + quad;
        bf16x8 ah[2], al[2], bh[4], bl[4];
#pragma unroll
        for (int i = 0; i < 2; i++) {
            int lt = (rt0 + i <= last_rt) ? i : (last_rt - rt0);
            int o = (lt * 8 + kb) * 128 + lm * 8;
            ah[i] = *(const bf16x8*)&zt[0][o];
            al[i] = *(const bf16x8*)&zt[1][o];
        }
#pragma unroll
        for (int j = 0; j < 4; j++) {
            long o = ((long)(wid * 4 + j) * 8 + kb) * 128 + lm * 8;
            bh[j] = *(const bf16x8*)&wd1h[o];
            bl[j] = *(const bf16x8*)&wd1l[o];
        }
#pragma unroll
        for (int i = 0; i < 2; i++)
#pragma unroll
            for (int j = 0; j < 4; j++) { MFMA3(acc[i][j], ah[i], al[i], bh[j], bl[j]); }
    }

    // epilogue A -> LDS tiled
#pragma unroll
    for (int i = 0; i < 2; i++)
#pragma unroll
        for (int j = 0; j < 4; j++) {
            int coln = wid * 64 + j * 16 + lm;
            float bi = bd1[coln];
#pragma unroll
            for (int r = 0; r < 4; r++) {
                int row = i * 16 + quad * 4 + r;
                float v = fmaxf(acc[i][j][r] + bi, 0.f);
                u16 h, l;
                split_bf16(v, h, l);
                int o = ((row >> 4) * 32 + (coln >> 3)) * 128 + ((row & 15) << 3) + (coln & 7);
                dsm[0][o] = h;
                dsm[1][o] = l;
            }
        }
    __syncthreads();

    // ---- stage B: out = d @ Wd2 + bd2, K=256 (KB=32, KC=8) ----
    f32x4 acc2[2][2];
#pragma unroll
    for (int i = 0; i < 2; i++)
#pragma unroll
        for (int j = 0; j < 2; j++) acc2[i][j] = (f32x4){0.f, 0.f, 0.f, 0.f};
#pragma unroll
    for (int kc = 0; kc < 8; kc++) {
        const int kb = kc * 4 + quad;
        bf16x8 ah[2], al[2], bh[2], bl[2];
#pragma unroll
        for (int i = 0; i < 2; i++) {
            int o = (i * 32 + kb) * 128 + lm * 8;
            ah[i] = *(const bf16x8*)&dsm[0][o];
            al[i] = *(const bf16x8*)&dsm[1][o];
        }
#pragma unroll
        for (int j = 0; j < 2; j++) {
            long o = ((long)(wid * 2 + j) * 32 + kb) * 128 + lm * 8;
            bh[j] = *(const bf16x8*)&wd2h[o];
            bl[j] = *(const bf16x8*)&wd2l[o];
        }
#pragma unroll
        for (int i = 0; i < 2; i++)
#pragma unroll
            for (int j = 0; j < 2; j++) { MFMA3(acc2[i][j], ah[i], al[i], bh[j], bl[j]); }
    }
#pragma unroll
    for (int i = 0; i < 2; i++)
#pragma unroll
        for (int j = 0; j < 2; j++) {
            int coln = wid * 32 + j * 16 + lm;
            float bi = bd2[coln];
#pragma unroll
            for (int r = 0; r < 4; r++) {
                int row = rt0 * 16 + i * 16 + quad * 4 + r;
                if (row < M) out[(long)row * 128 + coln] = acc2[i][j][r] + bi;
            }
        }
}

// ---------------- launch ----------------

extern "C" void kernel_launch(void* const* d_in, const int* in_sizes, int n_in,
                              void* d_out, int out_size, void* d_ws, size_t ws_size,
                              hipStream_t stream) {
    const float* x        = (const float*)d_in[0];
    const int* ei         = (const int*)d_in[1];   // int32 (harness integer convention)
    const float* W1       = (const float*)d_in[2];
    const float* b1       = (const float*)d_in[3];
    const float* W2       = (const float*)d_in[4];
    const float* b2       = (const float*)d_in[5];
    const float* Wd1      = (const float*)d_in[6];
    const float* bd1      = (const float*)d_in[7];
    const float* Wd2      = (const float*)d_in[8];
    const float* bd2      = (const float*)d_in[9];
    float* out            = (float*)d_out;

    const int N = in_sizes[0] / IN_CH;   // 50000 (multiple of 16)
    const int E = in_sizes[1] / 2;       // 800000

    char* p = (char*)d_ws;
    auto alloc = [&](size_t bytes) {
        char* r = p;
        p += (bytes + 255) & ~(size_t)255;
        return r;
    };
    int*      counts    = (int*)     alloc((size_t)(N + 1) * 4);
    int*      rowptr    = (int*)     alloc((size_t)(N + 1) * 4);
    int*      nxt       = (int*)     alloc((size_t)N * 4);
    int*      blocksums = (int*)     alloc(256 * 4);
    float*    dinv      = (float*)   alloc((size_t)N * 4);
    int*      col       = (int*)     alloc((size_t)E * 4);
    _Float16* xsh       = (_Float16*)alloc((size_t)N * IN_CH * 2);
    _Float16* zsh       = (_Float16*)alloc((size_t)N * LATENT * 2);
    u16*      w1t_hi    = (u16*)     alloc((size_t)IN_CH * HIDDEN * 2);
    u16*      w1t_lo    = (u16*)     alloc((size_t)IN_CH * HIDDEN * 2);
    u16*      w2t_hi    = (u16*)     alloc((size_t)HIDDEN * LATENT * 2);
    u16*      w2t_lo    = (u16*)     alloc((size_t)HIDDEN * LATENT * 2);
    u16*      wd1t_hi   = (u16*)     alloc((size_t)LATENT * HIDDEN * 2);
    u16*      wd1t_lo   = (u16*)     alloc((size_t)LATENT * HIDDEN * 2);
    u16*      wd2t_hi   = (u16*)     alloc((size_t)HIDDEN * IN_CH * 2);
    u16*      wd2t_lo   = (u16*)     alloc((size_t)HIDDEN * IN_CH * 2);

    const int nblk = (N + 255) / 256;            // 196
    const int total4 = N * (IN_CH / 4);
    const int chunks = (E + 255) / 256;          // edge chunks of 256
    const int nper = (N + 7) / 8;                // dst-range width per partition
    const int fblk = (N + 31) / 32;              // 1563

    hipMemsetAsync(counts, 0, (size_t)(N + 1) * 4, stream);
    hist_kernel<<<chunks * 8, 256, 0, stream>>>(ei, E, counts, nper);
    scan1_wsplit_kernel<<<nblk + 384, 256, 0, stream>>>(
        counts, rowptr, blocksums, dinv, N, nblk,
        W1, W2, Wd1, Wd2,
        w1t_hi, w1t_lo, w2t_hi, w2t_lo, wd1t_hi, wd1t_lo, wd2t_hi, wd2t_lo);
    scan3_prescale_kernel<<<(total4 + 255) / 256, 256, 0, stream>>>(
        rowptr, blocksums, nxt, x, dinv, xsh, N, total4, nblk);
    fill_kernel<<<chunks * 8, 256, 0, stream>>>(ei, E, nxt, col, nper);

    // enc_fused: [aggx prologue -> LDS] + zs = (relu(xa@W1+b1)@W2)*dinv
    enc_fused<<<fblk, 256, 0, stream>>>(xsh, rowptr, col, dinv,
                                        w1t_hi, w1t_lo, w2t_hi, w2t_lo,
                                        b1, zsh, N);
    // dec_fused: [agg64 prologue -> LDS] + out = relu(z@Wd1+bd1)@Wd2 + bd2
    dec_fused<<<fblk, 256, 0, stream>>>(zsh, rowptr, col, dinv, b2,
                                        wd1t_hi, wd1t_lo, wd2t_hi, wd2t_lo,
                                        bd1, bd2, out, N);
}

// Round 7
// 305.562 us; speedup vs baseline: 6.5204x; 1.0681x over previous
//
#include <hip/hip_runtime.h>

// GraphAE: 2x GCNConv encoder + 2-layer MLP decoder.
// N=50000, IN=128, HID=256, LAT=64, E=800000. fp32 in/out.
//
// R17 changes vs R16:
//  - LDS time-multiplexing: xa tile (16KB) aliases into o1 (32KB) in enc;
//    zt (8KB) aliases into dsm (32KB) in dec. xa/zt are dead once stage-A
//    frag reads finish; o1/dsm are born at the stage-A epilogue. One extra
//    __syncthreads() between. LDS 48->32KB (enc), 40->32KB (dec):
//    3->5 blocks/CU. R16 counters: enc_fused 96us at Occupancy 23.9%,
//    925 GB/s -> gather latency-bound on resident-wave count; this change
//    restores the memory parallelism the fusion destroyed.
//  - __launch_bounds__(256,5) pins VGPR <= 102 (have 68).
//  - R16: agg-into-GEMM producer-consumer fusion (FETCH 189->81MB confirmed),
//    wsplit rides scan1, scan2 folded into scan3. 7 dispatches.
//  - R14: f16 gather planes. R11: hist/fill dst-partition.
// (R15 grid-barrier fusion REVERTED: spin acquire = L2-inv storm on gfx950.)

#define IN_CH  128
#define HIDDEN 256
#define LATENT 64

typedef unsigned short u16;
typedef unsigned int u32;
typedef __bf16 bf16x8 __attribute__((ext_vector_type(8)));
typedef float f32x4 __attribute__((ext_vector_type(4)));
typedef _Float16 f16x4 __attribute__((ext_vector_type(4)));

static __device__ __forceinline__ float4 ld4(const float* p) {
    return *reinterpret_cast<const float4*>(p);
}
static __device__ __forceinline__ void acc4(float4& a, float4 v) {
    a.x += v.x; a.y += v.y; a.z += v.z; a.w += v.w;
}
static __device__ __forceinline__ f16x4 ldh4(const _Float16* p) {
    return *reinterpret_cast<const f16x4*>(p);
}
static __device__ __forceinline__ void acch(float4& a, f16x4 v) {
    a.x += (float)v[0]; a.y += (float)v[1]; a.z += (float)v[2]; a.w += (float)v[3];
}

// truncating hi/lo split: hi = top16(v); lo = top16(v - hi). v-hi exact.
static __device__ __forceinline__ void split_bf16(float v, u16& hi, u16& lo) {
    u32 b = __float_as_uint(v);
    hi = (u16)(b >> 16);
    float hf = __uint_as_float(b & 0xFFFF0000u);
    lo = (u16)(__float_as_uint(v - hf) >> 16);
}

// tiled-layout offset (elements). K multiple of 8; row tiles of 16.
static __device__ __forceinline__ long tix(int row, int k, int K) {
    return ((long)(row >> 4) * (K >> 3) + (k >> 3)) * 128 + ((row & 15) << 3) + (k & 7);
}

#define MFMA3(ACC, AH, AL, BH, BL)                                             \
    ACC = __builtin_amdgcn_mfma_f32_16x16x32_bf16(AH, BH, ACC, 0, 0, 0);       \
    ACC = __builtin_amdgcn_mfma_f32_16x16x32_bf16(AH, BL, ACC, 0, 0, 0);       \
    ACC = __builtin_amdgcn_mfma_f32_16x16x32_bf16(AL, BH, ACC, 0, 0, 0);

// ---------------- graph structure kernels ----------------

// Partitioned histogram: block b handles edge chunk (b>>3), dst range (b&7).
__global__ void hist_kernel(const int* __restrict__ ei, int E,
                            int* __restrict__ counts, int nper) {
    int part = blockIdx.x & 7;
    int e = (blockIdx.x >> 3) * 256 + threadIdx.x;
    if (e >= E) return;
    int d = ei[E + e];
    if ((unsigned)(d - part * nper) < (unsigned)nper) atomicAdd(&counts[d], 1);
}

// scan1 (blocks < nblk) with dinv emit; wsplit rides along (blocks >= nblk).
__global__ void scan1_wsplit_kernel(
    const int* __restrict__ counts, int* __restrict__ rowptr,
    int* __restrict__ blocksums, float* __restrict__ dinv, int N, int nblk,
    const float* __restrict__ W1, const float* __restrict__ W2,
    const float* __restrict__ Wd1, const float* __restrict__ Wd2,
    u16* __restrict__ w1h, u16* __restrict__ w1l, u16* __restrict__ w2h, u16* __restrict__ w2l,
    u16* __restrict__ wd1h, u16* __restrict__ wd1l, u16* __restrict__ wd2h, u16* __restrict__ wd2l) {
    __shared__ int sh[256];
    int tid = threadIdx.x;
    if ((int)blockIdx.x < nblk) {
        int i = blockIdx.x * 256 + tid;
        int v = (i < N) ? counts[i] : 0;
        if (i < N) dinv[i] = rsqrtf((float)v + 1.0f);
        sh[tid] = v;
        __syncthreads();
        for (int off = 1; off < 256; off <<= 1) {
            int t = (tid >= off) ? sh[tid - off] : 0;
            __syncthreads();
            sh[tid] += t;
            __syncthreads();
        }
        if (i < N) rowptr[i] = sh[tid] - v;
        if (tid == 255) blocksums[blockIdx.x] = sh[255];
    } else {
        int idx = ((int)blockIdx.x - nblk) * 256 + tid;
        if (idx < 98304) {
            const float* W; u16 *H, *L; int K, Nn, base;
            if (idx < 32768)      { W = W1;  H = w1h;  L = w1l;  K = 128; Nn = 256; base = idx; }
            else if (idx < 49152) { W = W2;  H = w2h;  L = w2l;  K = 256; Nn = 64;  base = idx - 32768; }
            else if (idx < 65536) { W = Wd1; H = wd1h; L = wd1l; K = 64;  Nn = 256; base = idx - 49152; }
            else                  { W = Wd2; H = wd2h; L = wd2l; K = 256; Nn = 128; base = idx - 65536; }
            int k = base / Nn, n = base % Nn;
            u16 h, l;
            split_bf16(W[base], h, l);
            long o = tix(n, k, K);
            H[o] = h;
            L[o] = l;
        }
    }
}

// scan3 (+inlined scan2: blockoffs[b] = sum blocksums[0..b)) + prescale.
__global__ void scan3_prescale_kernel(
    int* __restrict__ rowptr, const int* __restrict__ blocksums, int* __restrict__ next,
    const float* __restrict__ x, const float* __restrict__ dinv, _Float16* __restrict__ xsh,
    int N, int total4, int nblk) {
    __shared__ int sh[256];
    const int b = blockIdx.x;
    const int tid = threadIdx.x;
    int boff = 0;
    if (b < nblk) {
        int s = 0;
        for (int j = tid; j < b; j += 256) s += blocksums[j];
        sh[tid] = s;
        __syncthreads();
        for (int off = 128; off > 0; off >>= 1) {
            if (tid < off) sh[tid] += sh[tid + off];
            __syncthreads();
        }
        boff = sh[0];
        if (b == nblk - 1 && tid == 0) rowptr[N] = boff + blocksums[b];
    }
    int i = b * 256 + tid;
    if (b < nblk && i < N) {
        int r = rowptr[i] + boff;
        rowptr[i] = r;
        next[i] = r;
    }
    if (i < total4) {
        float s = dinv[i >> 5];
        float4 v = ld4(&x[(long)i * 4]);
        f16x4 h;
        h[0] = (_Float16)(v.x * s);
        h[1] = (_Float16)(v.y * s);
        h[2] = (_Float16)(v.z * s);
        h[3] = (_Float16)(v.w * s);
        *reinterpret_cast<f16x4*>(&xsh[(long)i * 4]) = h;
    }
}

// Partitioned CSR fill: block b handles edge chunk (b>>3), dst range (b&7).
__global__ void fill_kernel(const int* __restrict__ ei, int E,
                            int* __restrict__ next, int* __restrict__ col, int nper) {
    int part = blockIdx.x & 7;
    int e = (blockIdx.x >> 3) * 256 + threadIdx.x;
    if (e >= E) return;
    int d = ei[E + e];
    if ((unsigned)(d - part * nper) < (unsigned)nper) {
        int s = ei[e];
        int pos = atomicAdd(&next[d], 1);
        col[pos] = s;
    }
}

// ---------------- fused agg+encoder ----------------
// Prologue: each wave aggregates 8 nodes (f16 gather, fp32 acc, dinv scale)
// -> LDS bf16 hi/lo xa tile [32 x 128] ALIASED into the first 8KB of each o1
// plane (xa dead after stage-A frag reads; o1 born at stage-A epilogue).
// Then zs = (relu(xa@W1+b1) @ W2) * dinv. LDS total 32KB -> 5 blocks/CU.
__global__ __launch_bounds__(256, 5) void enc_fused(
    const _Float16* __restrict__ xsh, const int* __restrict__ rowptr,
    const int* __restrict__ col, const float* __restrict__ dinv,
    const u16* __restrict__ w1h, const u16* __restrict__ w1l,
    const u16* __restrict__ w2h, const u16* __restrict__ w2l,
    const float* __restrict__ b1, _Float16* __restrict__ zsh, int M) {
    __shared__ u16 o1[2][32 * 256];  // 32 KB; first 8KB of each plane = xa tile

    const int tid = threadIdx.x;
    const int wid = tid >> 6, lane = tid & 63, quad = lane >> 4, lm = lane & 15;
    const int rt0 = blockIdx.x * 2;
    const int last_rt = (M >> 4) - 1;
    u16* const xa0 = &o1[0][0];  // [32*128] tiled
    u16* const xa1 = &o1[1][0];

    // ---- agg prologue (aggx): 8 nodes per wave ----
    {
        const int slot = lane >> 5;
        const int c = (lane & 31) * 4;
        for (int r8 = 0; r8 < 8; r8++) {
            int node = blockIdx.x * 32 + wid * 8 + r8;
            if (node >= M) break;
            float4 a0 = make_float4(0.f, 0.f, 0.f, 0.f);
            float4 a1 = a0, a2 = a0, a3 = a0;
            if (slot == 0) acch(a0, ldh4(&xsh[(long)node * 128 + c]));
            int beg = rowptr[node];
            int end = rowptr[node + 1];
            for (int cb = beg; cb < end; cb += 64) {
                int cnt = min(64, end - cb);
                int cv = (lane < cnt) ? col[cb + lane] : 0;
                int full = cnt >> 1;
                int trips = (cnt + 1) >> 1;
                int t = 0;
                for (; t + 4 <= full; t += 4) {
                    int j = slot + 2 * t;
                    int s0 = __shfl(cv, j);
                    int s1 = __shfl(cv, j + 2);
                    int s2 = __shfl(cv, j + 4);
                    int s3 = __shfl(cv, j + 6);
                    f16x4 v0 = ldh4(&xsh[(long)s0 * 128 + c]);
                    f16x4 v1 = ldh4(&xsh[(long)s1 * 128 + c]);
                    f16x4 v2 = ldh4(&xsh[(long)s2 * 128 + c]);
                    f16x4 v3 = ldh4(&xsh[(long)s3 * 128 + c]);
                    acch(a0, v0); acch(a1, v1); acch(a2, v2); acch(a3, v3);
                }
                for (; t < trips; t++) {
                    int j = slot + 2 * t;
                    bool p = j < cnt;
                    int s = __shfl(cv, p ? j : 0);
                    if (p) acch(a0, ldh4(&xsh[(long)s * 128 + c]));
                }
            }
            acc4(a0, a1); acc4(a2, a3); acc4(a0, a2);
            a0.x += __shfl_xor(a0.x, 32);
            a0.y += __shfl_xor(a0.y, 32);
            a0.z += __shfl_xor(a0.z, 32);
            a0.w += __shfl_xor(a0.w, 32);
            if (slot == 0) {
                float di = dinv[node];
                a0.x *= di; a0.y *= di; a0.z *= di; a0.w *= di;
                ushort4 h, l;
                split_bf16(a0.x, h.x, l.x);
                split_bf16(a0.y, h.y, l.y);
                split_bf16(a0.z, h.z, l.z);
                split_bf16(a0.w, h.w, l.w);
                int row = wid * 8 + r8;
                int o = ((row >> 4) * 16 + (c >> 3)) * 128 + ((row & 15) << 3) + (c & 7);
                *(ushort4*)&xa0[o] = h;
                *(ushort4*)&xa1[o] = l;
            }
        }
    }
    __syncthreads();

    // ---- stage A: out1 = relu(xa @ W1 + b1), K=128 (KB=16, KC=4) ----
    f32x4 acc[2][4];
#pragma unroll
    for (int i = 0; i < 2; i++)
#pragma unroll
        for (int j = 0; j < 4; j++) acc[i][j] = (f32x4){0.f, 0.f, 0.f, 0.f};

#pragma unroll
    for (int kc = 0; kc < 4; kc++) {
        const int kb = kc * 4 + quad;
        bf16x8 ah[2], al[2], bh[4], bl[4];
#pragma unroll
        for (int i = 0; i < 2; i++) {
            int lt = (rt0 + i <= last_rt) ? i : (last_rt - rt0);
            int o = (lt * 16 + kb) * 128 + lm * 8;
            ah[i] = *(const bf16x8*)&xa0[o];
            al[i] = *(const bf16x8*)&xa1[o];
        }
#pragma unroll
        for (int j = 0; j < 4; j++) {
            long o = ((long)(wid * 4 + j) * 16 + kb) * 128 + lm * 8;
            bh[j] = *(const bf16x8*)&w1h[o];
            bl[j] = *(const bf16x8*)&w1l[o];
        }
#pragma unroll
        for (int i = 0; i < 2; i++)
#pragma unroll
            for (int j = 0; j < 4; j++) { MFMA3(acc[i][j], ah[i], al[i], bh[j], bl[j]); }
    }
    __syncthreads();  // xa (aliased below o1) dead only after ALL waves read it

    // epilogue A -> LDS tiled (overwrites xa region)
#pragma unroll
    for (int i = 0; i < 2; i++)
#pragma unroll
        for (int j = 0; j < 4; j++) {
            int coln = wid * 64 + j * 16 + lm;
            float bi = b1[coln];
#pragma unroll
            for (int r = 0; r < 4; r++) {
                int row = i * 16 + quad * 4 + r;
                float v = fmaxf(acc[i][j][r] + bi, 0.f);
                u16 h, l;
                split_bf16(v, h, l);
                int o = ((row >> 4) * 32 + (coln >> 3)) * 128 + ((row & 15) << 3) + (coln & 7);
                o1[0][o] = h;
                o1[1][o] = l;
            }
        }
    __syncthreads();

    // ---- stage B: zs = (out1 @ W2) * dinv, K=256 (KB=32, KC=8) ----
    f32x4 acc2[2];
    acc2[0] = (f32x4){0.f, 0.f, 0.f, 0.f};
    acc2[1] = (f32x4){0.f, 0.f, 0.f, 0.f};
#pragma unroll
    for (int kc = 0; kc < 8; kc++) {
        const int kb = kc * 4 + quad;
        bf16x8 ah[2], al[2], bh, bl;
#pragma unroll
        for (int i = 0; i < 2; i++) {
            int o = (i * 32 + kb) * 128 + lm * 8;
            ah[i] = *(const bf16x8*)&o1[0][o];
            al[i] = *(const bf16x8*)&o1[1][o];
        }
        {
            long o = ((long)wid * 32 + kb) * 128 + lm * 8;
            bh = *(const bf16x8*)&w2h[o];
            bl = *(const bf16x8*)&w2l[o];
        }
#pragma unroll
        for (int i = 0; i < 2; i++) { MFMA3(acc2[i], ah[i], al[i], bh, bl); }
    }
#pragma unroll
    for (int i = 0; i < 2; i++) {
        int coln = wid * 16 + lm;
#pragma unroll
        for (int r = 0; r < 4; r++) {
            int row = rt0 * 16 + i * 16 + quad * 4 + r;
            if (row < M) zsh[(long)row * 64 + coln] = (_Float16)(acc2[i][r] * dinv[row]);
        }
    }
}

// ---------------- fused agg+decoder ----------------
// Prologue: each wave aggregates 8 nodes of z = dinv*(zs+sum zs)+b2 -> LDS
// bf16 hi/lo z tile [32 x 64] ALIASED into dsm (first 4KB of each plane).
// Then out = relu(z@Wd1+bd1)@Wd2 + bd2. LDS total 32KB -> 5 blocks/CU.
__global__ __launch_bounds__(256, 5) void dec_fused(
    const _Float16* __restrict__ zsh, const int* __restrict__ rowptr,
    const int* __restrict__ col, const float* __restrict__ dinv,
    const float* __restrict__ b2,
    const u16* __restrict__ wd1h, const u16* __restrict__ wd1l,
    const u16* __restrict__ wd2h, const u16* __restrict__ wd2l,
    const float* __restrict__ bd1, const float* __restrict__ bd2,
    float* __restrict__ out, int M) {
    __shared__ u16 dsm[2][32 * 256];  // 32 KB; first 4KB of each plane = z tile

    const int tid = threadIdx.x;
    const int wid = tid >> 6, lane = tid & 63, quad = lane >> 4, lm = lane & 15;
    const int rt0 = blockIdx.x * 2;
    const int last_rt = (M >> 4) - 1;
    u16* const zt0 = &dsm[0][0];  // [32*64] tiled
    u16* const zt1 = &dsm[1][0];

    // ---- agg prologue (agg64): 8 nodes per wave ----
    {
        const int slot = lane >> 4;
        const int c = (lane & 15) * 4;
        for (int r8 = 0; r8 < 8; r8++) {
            int node = blockIdx.x * 32 + wid * 8 + r8;
            if (node >= M) break;
            float4 a0 = make_float4(0.f, 0.f, 0.f, 0.f);
            float4 a1 = a0, a2 = a0, a3 = a0;
            if (slot == 0) acch(a0, ldh4(&zsh[(long)node * 64 + c]));
            int beg = rowptr[node];
            int end = rowptr[node + 1];
            for (int cb = beg; cb < end; cb += 64) {
                int cnt = min(64, end - cb);
                int cv = (lane < cnt) ? col[cb + lane] : 0;
                int full = cnt >> 2;
                int trips = (cnt + 3) >> 2;
                int t = 0;
                for (; t + 4 <= full; t += 4) {
                    int j = slot + 4 * t;
                    int s0 = __shfl(cv, j);
                    int s1 = __shfl(cv, j + 4);
                    int s2 = __shfl(cv, j + 8);
                    int s3 = __shfl(cv, j + 12);
                    f16x4 v0 = ldh4(&zsh[(long)s0 * 64 + c]);
                    f16x4 v1 = ldh4(&zsh[(long)s1 * 64 + c]);
                    f16x4 v2 = ldh4(&zsh[(long)s2 * 64 + c]);
                    f16x4 v3 = ldh4(&zsh[(long)s3 * 64 + c]);
                    acch(a0, v0); acch(a1, v1); acch(a2, v2); acch(a3, v3);
                }
                for (; t < trips; t++) {
                    int j = slot + 4 * t;
                    bool p = j < cnt;
                    int s = __shfl(cv, p ? j : 0);
                    if (p) acch(a0, ldh4(&zsh[(long)s * 64 + c]));
                }
            }
            acc4(a0, a1); acc4(a2, a3); acc4(a0, a2);
            a0.x += __shfl_xor(a0.x, 16); a0.x += __shfl_xor(a0.x, 32);
            a0.y += __shfl_xor(a0.y, 16); a0.y += __shfl_xor(a0.y, 32);
            a0.z += __shfl_xor(a0.z, 16); a0.z += __shfl_xor(a0.z, 32);
            a0.w += __shfl_xor(a0.w, 16); a0.w += __shfl_xor(a0.w, 32);
            if (slot == 0) {
                float di = dinv[node];
                float4 bi = ld4(&b2[c]);
                a0.x = a0.x * di + bi.x;
                a0.y = a0.y * di + bi.y;
                a0.z = a0.z * di + bi.z;
                a0.w = a0.w * di + bi.w;
                ushort4 h, l;
                split_bf16(a0.x, h.x, l.x);
                split_bf16(a0.y, h.y, l.y);
                split_bf16(a0.z, h.z, l.z);
                split_bf16(a0.w, h.w, l.w);
                int row = wid * 8 + r8;
                int o = ((row >> 4) * 8 + (c >> 3)) * 128 + ((row & 15) << 3) + (c & 7);
                *(ushort4*)&zt0[o] = h;
                *(ushort4*)&zt1[o] = l;
            }
        }
    }
    __syncthreads();

    // ---- stage A: d = relu(z @ Wd1 + bd1), K=64 (KB=8, KC=2) ----
    f32x4 acc[2][4];
#pragma unroll
    for (int i = 0; i < 2; i++)
#pragma unroll
        for (int j = 0; j < 4; j++) acc[i][j] = (f32x4){0.f, 0.f, 0.f, 0.f};

#pragma unroll
    for (int kc = 0; kc < 2; kc++) {
        const int kb = kc * 4 + quad;
        bf16x8 ah[2], al[2], bh[4], bl[4];
#pragma unroll
        for (int i = 0; i < 2; i++) {
            int lt = (rt0 + i <= last_rt) ? i : (last_rt - rt0);
            int o = (lt * 8 + kb) * 128 + lm * 8;
            ah[i] = *(const bf16x8*)&zt0[o];
            al[i] = *(const bf16x8*)&zt1[o];
        }
#pragma unroll
        for (int j = 0; j < 4; j++) {
            long o = ((long)(wid * 4 + j) * 8 + kb) * 128 + lm * 8;
            bh[j] = *(const bf16x8*)&wd1h[o];
            bl[j] = *(const bf16x8*)&wd1l[o];
        }
#pragma unroll
        for (int i = 0; i < 2; i++)
#pragma unroll
            for (int j = 0; j < 4; j++) { MFMA3(acc[i][j], ah[i], al[i], bh[j], bl[j]); }
    }
    __syncthreads();  // zt (aliased below dsm) dead only after ALL waves read it

    // epilogue A -> LDS tiled (overwrites zt region)
#pragma unroll
    for (int i = 0; i < 2; i++)
#pragma unroll
        for (int j = 0; j < 4; j++) {
            int coln = wid * 64 + j * 16 + lm;
            float bi = bd1[coln];
#pragma unroll
            for (int r = 0; r < 4; r++) {
                int row = i * 16 + quad * 4 + r;
                float v = fmaxf(acc[i][j][r] + bi, 0.f);
                u16 h, l;
                split_bf16(v, h, l);
                int o = ((row >> 4) * 32 + (coln >> 3)) * 128 + ((row & 15) << 3) + (coln & 7);
                dsm[0][o] = h;
                dsm[1][o] = l;
            }
        }
    __syncthreads();

    // ---- stage B: out = d @ Wd2 + bd2, K=256 (KB=32, KC=8) ----
    f32x4 acc2[2][2];
#pragma unroll
    for (int i = 0; i < 2; i++)
#pragma unroll
        for (int j = 0; j < 2; j++) acc2[i][j] = (f32x4){0.f, 0.f, 0.f, 0.f};
#pragma unroll
    for (int kc = 0; kc < 8; kc++) {
        const int kb = kc * 4 + quad;
        bf16x8 ah[2], al[2], bh[2], bl[2];
#pragma unroll
        for (int i = 0; i < 2; i++) {
            int o = (i * 32 + kb) * 128 + lm * 8;
            ah[i] = *(const bf16x8*)&dsm[0][o];
            al[i] = *(const bf16x8*)&dsm[1][o];
        }
#pragma unroll
        for (int j = 0; j < 2; j++) {
            long o = ((long)(wid * 2 + j) * 32 + kb) * 128 + lm * 8;
            bh[j] = *(const bf16x8*)&wd2h[o];
            bl[j] = *(const bf16x8*)&wd2l[o];
        }
#pragma unroll
        for (int i = 0; i < 2; i++)
#pragma unroll
            for (int j = 0; j < 2; j++) { MFMA3(acc2[i][j], ah[i], al[i], bh[j], bl[j]); }
    }
#pragma unroll
    for (int i = 0; i < 2; i++)
#pragma unroll
        for (int j = 0; j < 2; j++) {
            int coln = wid * 32 + j * 16 + lm;
            float bi = bd2[coln];
#pragma unroll
            for (int r = 0; r < 4; r++) {
                int row = rt0 * 16 + i * 16 + quad * 4 + r;
                if (row < M) out[(long)row * 128 + coln] = acc2[i][j][r] + bi;
            }
        }
}

// ---------------- launch ----------------

extern "C" void kernel_launch(void* const* d_in, const int* in_sizes, int n_in,
                              void* d_out, int out_size, void* d_ws, size_t ws_size,
                              hipStream_t stream) {
    const float* x        = (const float*)d_in[0];
    const int* ei         = (const int*)d_in[1];   // int32 (harness integer convention)
    const float* W1       = (const float*)d_in[2];
    const float* b1       = (const float*)d_in[3];
    const float* W2       = (const float*)d_in[4];
    const float* b2       = (const float*)d_in[5];
    const float* Wd1      = (const float*)d_in[6];
    const float* bd1      = (const float*)d_in[7];
    const float* Wd2      = (const float*)d_in[8];
    const float* bd2      = (const float*)d_in[9];
    float* out            = (float*)d_out;

    const int N = in_sizes[0] / IN_CH;   // 50000 (multiple of 16)
    const int E = in_sizes[1] / 2;       // 800000

    char* p = (char*)d_ws;
    auto alloc = [&](size_t bytes) {
        char* r = p;
        p += (bytes + 255) & ~(size_t)255;
        return r;
    };
    int*      counts    = (int*)     alloc((size_t)(N + 1) * 4);
    int*      rowptr    = (int*)     alloc((size_t)(N + 1) * 4);
    int*      nxt       = (int*)     alloc((size_t)N * 4);
    int*      blocksums = (int*)     alloc(256 * 4);
    float*    dinv      = (float*)   alloc((size_t)N * 4);
    int*      col       = (int*)     alloc((size_t)E * 4);
    _Float16* xsh       = (_Float16*)alloc((size_t)N * IN_CH * 2);
    _Float16* zsh       = (_Float16*)alloc((size_t)N * LATENT * 2);
    u16*      w1t_hi    = (u16*)     alloc((size_t)IN_CH * HIDDEN * 2);
    u16*      w1t_lo    = (u16*)     alloc((size_t)IN_CH * HIDDEN * 2);
    u16*      w2t_hi    = (u16*)     alloc((size_t)HIDDEN * LATENT * 2);
    u16*      w2t_lo    = (u16*)     alloc((size_t)HIDDEN * LATENT * 2);
    u16*      wd1t_hi   = (u16*)     alloc((size_t)LATENT * HIDDEN * 2);
    u16*      wd1t_lo   = (u16*)     alloc((size_t)LATENT * HIDDEN * 2);
    u16*      wd2t_hi   = (u16*)     alloc((size_t)HIDDEN * IN_CH * 2);
    u16*      wd2t_lo   = (u16*)     alloc((size_t)HIDDEN * IN_CH * 2);

    const int nblk = (N + 255) / 256;            // 196
    const int total4 = N * (IN_CH / 4);
    const int chunks = (E + 255) / 256;          // edge chunks of 256
    const int nper = (N + 7) / 8;                // dst-range width per partition
    const int fblk = (N + 31) / 32;              // 1563

    hipMemsetAsync(counts, 0, (size_t)(N + 1) * 4, stream);
    hist_kernel<<<chunks * 8, 256, 0, stream>>>(ei, E, counts, nper);
    scan1_wsplit_kernel<<<nblk + 384, 256, 0, stream>>>(
        counts, rowptr, blocksums, dinv, N, nblk,
        W1, W2, Wd1, Wd2,
        w1t_hi, w1t_lo, w2t_hi, w2t_lo, wd1t_hi, wd1t_lo, wd2t_hi, wd2t_lo);
    scan3_prescale_kernel<<<(total4 + 255) / 256, 256, 0, stream>>>(
        rowptr, blocksums, nxt, x, dinv, xsh, N, total4, nblk);
    fill_kernel<<<chunks * 8, 256, 0, stream>>>(ei, E, nxt, col, nper);

    // enc_fused: [aggx prologue -> LDS] + zs = (relu(xa@W1+b1)@W2)*dinv
    enc_fused<<<fblk, 256, 0, stream>>>(xsh, rowptr, col, dinv,
                                        w1t_hi, w1t_lo, w2t_hi, w2t_lo,
                                        b1, zsh, N);
    // dec_fused: [agg64 prologue -> LDS] + out = relu(z@Wd1+bd1)@Wd2 + bd2
    dec_fused<<<fblk, 256, 0, stream>>>(zsh, rowptr, col, dinv, b2,
                                        wd1t_hi, wd1t_lo, wd2t_hi, wd2t_lo,
                                        bd1, bd2, out, N);
}